// Round 14
// baseline (142.613 us; speedup 1.0000x reference)
//
#include <hip/hip_runtime.h>
#include <hip/hip_bf16.h>

#define NN 50000
#define EE 800000
#define GG 32
#define SCB 512

// bucket sort geometry (bucket = 64 dst nodes = one layer-block)
#define BSH 6
#define NBUK 782                      // ceil(50000/64)
#define NBLK1 256                     // edge blocks in pass 1
#define EPB (EE / NBLK1)              // 3125 edges per block
#define MH (NBUK * NBLK1)             // 200192 counters
#define NB2 ((MH + SCB - 1) / SCB)    // 391 scan blocks
#define CAP2 2048                     // max edges per bucket (mean 1023)

#define B_PREP ((NN + 255) / 256)                 // 196
#define TOTW (64 * 32 + 128 * 96 + 256 * 224)     // 71680
#define B_WTP ((TOTW + 255) / 256)                // 280

using short8 = __attribute__((ext_vector_type(8))) short;
using f32x4  = __attribute__((ext_vector_type(4))) float;

__device__ __forceinline__ ushort f2bf(float f) {
    __hip_bfloat16 hb = __float2bfloat16(f);
    return *reinterpret_cast<ushort*>(&hb);
}

__device__ __forceinline__ void acc8(uint4 v, float* a) {
    a[0] += __uint_as_float(v.x << 16); a[1] += __uint_as_float(v.x & 0xffff0000u);
    a[2] += __uint_as_float(v.y << 16); a[3] += __uint_as_float(v.y & 0xffff0000u);
    a[4] += __uint_as_float(v.z << 16); a[5] += __uint_as_float(v.z & 0xffff0000u);
    a[6] += __uint_as_float(v.w << 16); a[7] += __uint_as_float(v.w & 0xffff0000u);
}

// Wt[n][k'] = W[k][n]; mode 1 = fold W3 rows 200:208 into 64:72;
// mode 2 = layer-2 K-permutation so A-layout is [agg1(8)|aggh1(64)].
__device__ __forceinline__ void wtp_one(const float* W, ushort* Wt, int K, int F,
                                        int KPAD, int mode, int idx) {
    int n = idx / KPAD, k = idx - n * KPAD;
    float v = 0.f;
    if (k < K) {
        int ko = k;
        if (mode == 2) ko = (k < 8) ? (k + 64) : (k - 8);
        v = W[(size_t)ko * F + n];
        if (mode == 1 && ko >= 64 && ko < 72) v += W[(size_t)(ko + 136) * F + n];
    }
    Wt[idx] = f2bf(v);
}

// ---------------- fused setup: bhist | inp-build | Wt build | pooled init ----------------

__global__ __launch_bounds__(256) void setup_k(
        const int* __restrict__ edst, int* __restrict__ hist,
        const float* __restrict__ nrm, const float* __restrict__ pos,
        const float* __restrict__ x, ushort* __restrict__ inpb,
        const float* __restrict__ W1, ushort* __restrict__ Wt1,
        const float* __restrict__ W2, ushort* __restrict__ Wt2,
        const float* __restrict__ W3, ushort* __restrict__ Wt3,
        float* __restrict__ pooled) {
    int blk = blockIdx.x, tid = threadIdx.x;
    if (blk < NBLK1) {
        __shared__ uint cnt[NBUK];
        for (int i = tid; i < NBUK; i += 256) cnt[i] = 0;
        __syncthreads();
        int base = blk * EPB;
        for (int i = tid; i < EPB; i += 256)
            atomicAdd(&cnt[(uint)edst[base + i] >> BSH], 1u);
        __syncthreads();
        for (int b = tid; b < NBUK; b += 256)
            hist[(size_t)b * NBLK1 + blk] = (int)cnt[b];
    } else if (blk < NBLK1 + B_PREP) {
        int i = (blk - NBLK1) * 256 + tid;
        if (i < NN) {
            float v[8];
            v[0] = nrm[i * 3]; v[1] = nrm[i * 3 + 1]; v[2] = nrm[i * 3 + 2];
            v[3] = pos[i * 3]; v[4] = pos[i * 3 + 1]; v[5] = pos[i * 3 + 2];
            v[6] = x[i * 2];   v[7] = x[i * 2 + 1];
            uint4 d;
            d.x = (uint)f2bf(v[0]) | ((uint)f2bf(v[1]) << 16);
            d.y = (uint)f2bf(v[2]) | ((uint)f2bf(v[3]) << 16);
            d.z = (uint)f2bf(v[4]) | ((uint)f2bf(v[5]) << 16);
            d.w = (uint)f2bf(v[6]) | ((uint)f2bf(v[7]) << 16);
            *reinterpret_cast<uint4*>(&inpb[(size_t)i * 8]) = d;
        }
    } else if (blk < NBLK1 + B_PREP + B_WTP) {
        int idx = (blk - NBLK1 - B_PREP) * 256 + tid;
        if (idx < 64 * 32) { wtp_one(W1, Wt1, 8, 64, 32, 0, idx); return; }
        idx -= 64 * 32;
        if (idx < 128 * 96) { wtp_one(W2, Wt2, 72, 128, 96, 2, idx); return; }
        idx -= 128 * 96;
        if (idx < 256 * 224) wtp_one(W3, Wt3, 200, 256, 224, 1, idx);
    } else {
        for (int q = tid; q < GG * 256; q += 256) pooled[q] = 0.f;
    }
}

// ---------------- generic 3-phase exclusive scan ----------------

__global__ __launch_bounds__(SCB) void scan1_k(const int* __restrict__ in,
                                               int* __restrict__ bsum, int M) {
    __shared__ int ws[SCB / 64];
    int tid = threadIdx.x, lane = tid & 63, w = tid >> 6;
    int i = blockIdx.x * SCB + tid;
    int s = (i < M) ? in[i] : 0;
    #pragma unroll
    for (int off = 32; off >= 1; off >>= 1) s += __shfl_down(s, off, 64);
    if (lane == 0) ws[w] = s;
    __syncthreads();
    if (tid == 0) {
        int t = 0;
        #pragma unroll
        for (int j = 0; j < SCB / 64; j++) t += ws[j];
        bsum[blockIdx.x] = t;
    }
}

__global__ __launch_bounds__(64) void scan2g_k(int* __restrict__ bsum, int nb) {
    int lane = threadIdx.x;
    int carry = 0;
    for (int base = 0; base < nb; base += 64) {
        int v = (base + lane < nb) ? bsum[base + lane] : 0;
        int s = v;
        #pragma unroll
        for (int off = 1; off < 64; off <<= 1) {
            int t = __shfl_up(s, off, 64);
            if (lane >= off) s += t;
        }
        if (base + lane < nb) bsum[base + lane] = carry + s - v;
        carry += __shfl(s, 63, 64);
    }
}

__global__ __launch_bounds__(SCB) void scan3g_k(const int* __restrict__ in,
                                                const int* __restrict__ bsum,
                                                int* __restrict__ out, int M) {
    __shared__ int ws[SCB / 64];
    int tid = threadIdx.x, lane = tid & 63, w = tid >> 6;
    int i = blockIdx.x * SCB + tid;
    int v = (i < M) ? in[i] : 0;
    int s = v;
    #pragma unroll
    for (int off = 1; off < 64; off <<= 1) {
        int t = __shfl_up(s, off, 64);
        if (lane >= off) s += t;
    }
    if (lane == 63) ws[w] = s;
    __syncthreads();
    if (w == 0 && lane < SCB / 64) {
        int t = ws[lane];
        #pragma unroll
        for (int off = 1; off < SCB / 64; off <<= 1) {
            int u = __shfl_up(t, off, 64);
            if (lane >= off) t += u;
        }
        ws[lane] = t;
    }
    __syncthreads();
    if (i < M) out[i] = (w ? ws[w - 1] : 0) + s - v + bsum[blockIdx.x];
}

// ---------------- bucket sort pass 1 ----------------

__global__ __launch_bounds__(256) void bsort1_k(const int* __restrict__ esrc,
                                                const int* __restrict__ edst,
                                                const int* __restrict__ ofs,
                                                uint* __restrict__ packed) {
    __shared__ uint cnt[1024];
    __shared__ uint lofs0[1024];
    __shared__ uint goff[NBUK];
    __shared__ uint stage[EPB];
    __shared__ uint wsum[4];
    int tid = threadIdx.x, blk = blockIdx.x;
    int lane = tid & 63, wv = tid >> 6;

    for (int i = tid; i < 1024; i += 256) cnt[i] = 0;
    __syncthreads();
    int base = blk * EPB;
    for (int i = tid; i < EPB; i += 256)
        atomicAdd(&cnt[(uint)edst[base + i] >> BSH], 1u);
    __syncthreads();

    uint c0 = cnt[tid * 4 + 0], c1 = cnt[tid * 4 + 1];
    uint c2 = cnt[tid * 4 + 2], c3 = cnt[tid * 4 + 3];
    uint ts = c0 + c1 + c2 + c3;
    uint sc = ts;
    #pragma unroll
    for (int off = 1; off < 64; off <<= 1) {
        uint t = __shfl_up(sc, off, 64);
        if (lane >= off) sc += t;
    }
    if (lane == 63) wsum[wv] = sc;
    __syncthreads();
    uint wbase = 0;
    for (int j = 0; j < wv; j++) wbase += wsum[j];
    uint run = wbase + sc - ts;
    lofs0[tid * 4 + 0] = run;
    lofs0[tid * 4 + 1] = run + c0;
    lofs0[tid * 4 + 2] = run + c0 + c1;
    lofs0[tid * 4 + 3] = run + c0 + c1 + c2;
    cnt[tid * 4 + 0] = run;
    cnt[tid * 4 + 1] = run + c0;
    cnt[tid * 4 + 2] = run + c0 + c1;
    cnt[tid * 4 + 3] = run + c0 + c1 + c2;
    for (int b = tid; b < NBUK; b += 256)
        goff[b] = (uint)ofs[(size_t)b * NBLK1 + blk];
    __syncthreads();

    for (int i = tid; i < EPB; i += 256) {
        int d = edst[base + i];
        uint b = (uint)d >> BSH;
        uint pos = atomicAdd(&cnt[b], 1u);
        stage[pos] = (b << 22) | ((uint)(d & 63) << 16) | (uint)esrc[base + i];
    }
    __syncthreads();

    for (int i = tid; i < EPB; i += 256) {
        uint p = stage[i];
        uint b = p >> 22;
        packed[goff[b] + ((uint)i - lofs0[b])] = p & 0x3FFFFFu;
    }
}

// ---------------- bucket sort pass 2 ----------------

__global__ __launch_bounds__(256) void bsort2_k(const uint* __restrict__ packed,
                                                const int* __restrict__ ofs,
                                                ushort* __restrict__ col,
                                                int* __restrict__ rowptr) {
    __shared__ uint buf[CAP2];
    __shared__ ushort srt[CAP2];
    __shared__ uint fcnt[64], fofs[64];
    int b = blockIdx.x, tid = threadIdx.x;
    uint g0 = (uint)ofs[(size_t)b * NBLK1];
    uint g1 = (b + 1 < NBUK) ? (uint)ofs[(size_t)(b + 1) * NBLK1] : (uint)EE;
    uint n = g1 - g0;
    if (tid < 64) fcnt[tid] = 0;
    __syncthreads();
    for (uint i = tid; i < n; i += 256) {
        uint p = packed[g0 + i];
        buf[i] = p;
        atomicAdd(&fcnt[(p >> 16) & 63], 1u);
    }
    __syncthreads();
    if (tid < 64) {
        uint v = fcnt[tid], s = v;
        #pragma unroll
        for (int off = 1; off < 64; off <<= 1) {
            uint t = __shfl_up(s, off, 64);
            if (tid >= off) s += t;
        }
        uint e0 = s - v;
        fofs[tid] = e0;
        int node = (b << BSH) + tid;
        if (node < NN) rowptr[node] = (int)(g0 + e0);
    }
    if (b == NBUK - 1 && tid == 0) rowptr[NN] = EE;
    __syncthreads();
    for (uint i = tid; i < n; i += 256) {
        uint p = buf[i];
        uint pos = atomicAdd(&fofs[(p >> 16) & 63], 1u);
        srt[pos] = (ushort)(p & 0xFFFFu);
    }
    __syncthreads();
    for (uint i = tid; i < n; i += 256) col[g0 + i] = srt[i];
}

// ---------------- fused layer (layers 1/2): gather-aggregate + MFMA ----------------
// R8 structure (proven). Block = 64 nodes, 512 threads = 8 waves.
// Fragment layouts (m89/m91-verified): A/B lane l -> row l&15, k=(l>>4)*8+e;
// C/D col=lane&15, row=(lane>>4)*4+reg.

template <int K, int KPAD, int LDA, int F, int WPA, int WPB, int WG>
__global__ __launch_bounds__(512) void layer_k(
        const ushort* __restrict__ preA, const ushort* __restrict__ preB,
        const ushort* __restrict__ gsrc,
        const int* __restrict__ rowptr, const ushort* __restrict__ col,
        const ushort* __restrict__ Wt, const float* __restrict__ bias,
        ushort* __restrict__ aggout, ushort* __restrict__ out, int N) {
    constexpr int WPRE = WPA + WPB;
    constexpr int NU4 = WG / 8;
    constexpr int TPN = (NU4 < 8) ? NU4 : 8;
    constexpr int U4PT = NU4 / TPN;
    constexpr int KS = KPAD / 32;
    constexpr int FW = F / 4;
    constexpr int NT = FW / 16;

    __shared__ ushort At[64 * LDA];

    const int node0 = blockIdx.x * 64;
    const int tid = threadIdx.x;
    const int lane = tid & 63;
    const int wv = tid >> 6;
    const int wm = wv & 1;
    const int wn = wv >> 1;

    // ---- phase A: gather-aggregate into At[., WPRE..WPRE+WG) ----
    {
        int m = tid / TPN;
        int j = tid - m * TPN;
        if (m < 64) {
            int i = node0 + m;
            float ga0[U4PT * 8], ga1[U4PT * 8];
            #pragma unroll
            for (int q = 0; q < U4PT * 8; q++) { ga0[q] = 0.f; ga1[q] = 0.f; }
            if (i < N) {
                int e0 = rowptr[i], e1 = rowptr[i + 1];
                int e = e0;
                for (; e + 1 < e1; e += 2) {
                    int s0 = col[e], s1 = col[e + 1];
                    #pragma unroll
                    for (int u = 0; u < U4PT; u++) {
                        uint4 v0 = *reinterpret_cast<const uint4*>(
                            &gsrc[(size_t)s0 * WG + (j * U4PT + u) * 8]);
                        uint4 v1 = *reinterpret_cast<const uint4*>(
                            &gsrc[(size_t)s1 * WG + (j * U4PT + u) * 8]);
                        acc8(v0, ga0 + u * 8);
                        acc8(v1, ga1 + u * 8);
                    }
                }
                if (e < e1) {
                    int s0 = col[e];
                    #pragma unroll
                    for (int u = 0; u < U4PT; u++) {
                        uint4 v0 = *reinterpret_cast<const uint4*>(
                            &gsrc[(size_t)s0 * WG + (j * U4PT + u) * 8]);
                        acc8(v0, ga0 + u * 8);
                    }
                }
            }
            #pragma unroll
            for (int u = 0; u < U4PT; u++) {
                uint4 o;
                o.x = (uint)f2bf(ga0[u*8+0] + ga1[u*8+0]) | ((uint)f2bf(ga0[u*8+1] + ga1[u*8+1]) << 16);
                o.y = (uint)f2bf(ga0[u*8+2] + ga1[u*8+2]) | ((uint)f2bf(ga0[u*8+3] + ga1[u*8+3]) << 16);
                o.z = (uint)f2bf(ga0[u*8+4] + ga1[u*8+4]) | ((uint)f2bf(ga0[u*8+5] + ga1[u*8+5]) << 16);
                o.w = (uint)f2bf(ga0[u*8+6] + ga1[u*8+6]) | ((uint)f2bf(ga0[u*8+7] + ga1[u*8+7]) << 16);
                *reinterpret_cast<uint4*>(&At[m * LDA + WPRE + (j * U4PT + u) * 8]) = o;
                if (aggout != nullptr && i < N)
                    *reinterpret_cast<uint4*>(&aggout[(size_t)i * WG + (j * U4PT + u) * 8]) = o;
            }
        }
    }

    // ---- pre-staged cols [0, WPRE) from global ----
    if constexpr (WPRE > 0) {
        constexpr int NP = WPRE / 8;
        for (int idx = tid; idx < 64 * NP; idx += 512) {
            int m = idx / NP, q = idx - m * NP;
            int i = node0 + m;
            uint4 v = make_uint4(0, 0, 0, 0);
            if (i < N) {
                int c = q * 8;
                if (c < WPA) v = *reinterpret_cast<const uint4*>(&preA[(size_t)i * WPA + c]);
                else v = *reinterpret_cast<const uint4*>(&preB[(size_t)i * WPB + (c - WPA)]);
            }
            *reinterpret_cast<uint4*>(&At[m * LDA + q * 8]) = v;
        }
    }
    // ---- zero pad [K, LDA) ----
    {
        constexpr int PAD = LDA - K;
        for (int idx = tid; idx < 64 * PAD; idx += 512) {
            int m = idx / PAD, k = K + (idx - m * PAD);
            At[m * LDA + k] = 0;
        }
    }
    __syncthreads();

    // ---- phase B: MFMA ----
    const int r15 = lane & 15, kg = lane >> 4;

    short8 a[2][KS];
    #pragma unroll
    for (int s = 0; s < 2; s++)
        #pragma unroll
        for (int kc = 0; kc < KS; kc++)
            a[s][kc] = *reinterpret_cast<const short8*>(
                &At[(wm * 32 + s * 16 + r15) * LDA + kg * 8 + kc * 32]);

    f32x4 acc[2][NT];
    #pragma unroll
    for (int s = 0; s < 2; s++)
        #pragma unroll
        for (int nt = 0; nt < NT; nt++) acc[s][nt] = (f32x4){0.f, 0.f, 0.f, 0.f};

    const ushort* wbase = &Wt[(size_t)(wn * FW + r15) * KPAD + kg * 8];
    #pragma unroll
    for (int nt = 0; nt < NT; nt++) {
        short8 b[KS];
        #pragma unroll
        for (int kc = 0; kc < KS; kc++)
            b[kc] = *reinterpret_cast<const short8*>(
                wbase + (size_t)nt * 16 * KPAD + kc * 32);
        #pragma unroll
        for (int kc = 0; kc < KS; kc++) {
            acc[0][nt] = __builtin_amdgcn_mfma_f32_16x16x32_bf16(a[0][kc], b[kc], acc[0][nt], 0, 0, 0);
            acc[1][nt] = __builtin_amdgcn_mfma_f32_16x16x32_bf16(a[1][kc], b[kc], acc[1][nt], 0, 0, 0);
        }
    }

    #pragma unroll
    for (int s = 0; s < 2; s++)
        #pragma unroll
        for (int nt = 0; nt < NT; nt++) {
            int colg = wn * FW + nt * 16 + r15;
            float bv = bias[colg];
            #pragma unroll
            for (int reg = 0; reg < 4; reg++) {
                int row = node0 + wm * 32 + s * 16 + kg * 4 + reg;
                if (row < N) {
                    float v = fmaxf(acc[s][nt][reg] + bv, 0.f);
                    out[(size_t)row * F + colg] = f2bf(v);
                }
            }
        }
}

// ---------------- L3 standalone gather: aggh2 = A @ h2 ----------------
// Barrier-free, LDS-free, 256-thread blocks, 8 threads/node (32B slice pair
// each -> per-instruction coalescing = 8 rows x 128B). 2-edge batch with 4
// fully independent uint4 loads feeding 2 SEPARATE accumulator arrays (R13
// lesson: shared accumulators let the compiler serialize the batch; VGPR must
// rise). Grid 1563 blocks -> ~24 waves/CU (2.5x the fused kernel's 9).

__global__ __launch_bounds__(256) void gather3_k(const int* __restrict__ rowptr,
                                                 const ushort* __restrict__ col,
                                                 const ushort* __restrict__ h2,
                                                 ushort* __restrict__ aggh2, int N) {
    int m = blockIdx.x * 32 + (threadIdx.x >> 3);
    int j = threadIdx.x & 7;
    if (m >= N) return;
    const size_t jo = (size_t)j * 16;
    float a0[16], a1[16];
    #pragma unroll
    for (int q = 0; q < 16; q++) { a0[q] = 0.f; a1[q] = 0.f; }
    int e0 = rowptr[m], e1 = rowptr[m + 1];
    int e = e0;
    for (; e + 1 < e1; e += 2) {
        int s0 = col[e], s1 = col[e + 1];
        uint4 v00 = *reinterpret_cast<const uint4*>(&h2[(size_t)s0 * 128 + jo]);
        uint4 v01 = *reinterpret_cast<const uint4*>(&h2[(size_t)s0 * 128 + jo + 8]);
        uint4 v10 = *reinterpret_cast<const uint4*>(&h2[(size_t)s1 * 128 + jo]);
        uint4 v11 = *reinterpret_cast<const uint4*>(&h2[(size_t)s1 * 128 + jo + 8]);
        acc8(v00, a0); acc8(v01, a0 + 8);
        acc8(v10, a1); acc8(v11, a1 + 8);
    }
    if (e < e1) {
        int s0 = col[e];
        uint4 v00 = *reinterpret_cast<const uint4*>(&h2[(size_t)s0 * 128 + jo]);
        uint4 v01 = *reinterpret_cast<const uint4*>(&h2[(size_t)s0 * 128 + jo + 8]);
        acc8(v00, a0); acc8(v01, a0 + 8);
    }
    uint4 o0, o1;
    o0.x = (uint)f2bf(a0[0] + a1[0])  | ((uint)f2bf(a0[1] + a1[1]) << 16);
    o0.y = (uint)f2bf(a0[2] + a1[2])  | ((uint)f2bf(a0[3] + a1[3]) << 16);
    o0.z = (uint)f2bf(a0[4] + a1[4])  | ((uint)f2bf(a0[5] + a1[5]) << 16);
    o0.w = (uint)f2bf(a0[6] + a1[6])  | ((uint)f2bf(a0[7] + a1[7]) << 16);
    o1.x = (uint)f2bf(a0[8] + a1[8])  | ((uint)f2bf(a0[9] + a1[9]) << 16);
    o1.y = (uint)f2bf(a0[10] + a1[10]) | ((uint)f2bf(a0[11] + a1[11]) << 16);
    o1.z = (uint)f2bf(a0[12] + a1[12]) | ((uint)f2bf(a0[13] + a1[13]) << 16);
    o1.w = (uint)f2bf(a0[14] + a1[14]) | ((uint)f2bf(a0[15] + a1[15]) << 16);
    *reinterpret_cast<uint4*>(&aggh2[(size_t)m * 128 + jo]) = o0;
    *reinterpret_cast<uint4*>(&aggh2[(size_t)m * 128 + jo + 8]) = o1;
}

// ---------------- L3 MFMA + fused pool ----------------
// 64 nodes/block; stages A = [aggh1(64) | agg1(8) | aggh2(128)], zero-pad to
// KPAD=224 (Wt3 mode-1 natural K-order). MFMA + segmented max pool, identical
// math to the proven fused path.

__global__ __launch_bounds__(512) void layer3b_k(
        const ushort* __restrict__ aggh1, const ushort* __restrict__ agg1,
        const ushort* __restrict__ aggh2,
        const ushort* __restrict__ Wt, const float* __restrict__ bias,
        const int* __restrict__ batch, float* __restrict__ pooled, int N) {
    constexpr int KPAD = 224, LDA = 264, F = 256;
    constexpr int KS = KPAD / 32;       // 7
    constexpr int FW = F / 4;           // 64
    constexpr int NT = FW / 16;         // 4

    __shared__ ushort At[64 * LDA];
    __shared__ int batchv[64];

    const int node0 = blockIdx.x * 64;
    const int tid = threadIdx.x;
    const int lane = tid & 63;
    const int wv = tid >> 6;
    const int wm = wv & 1;
    const int wn = wv >> 1;

    // ---- stage A ----
    for (int idx = tid; idx < 64 * 8; idx += 512) {      // aggh1 -> [0,64)
        int m = idx >> 3, q = idx & 7;
        int i = node0 + m;
        uint4 v = make_uint4(0, 0, 0, 0);
        if (i < N) v = *reinterpret_cast<const uint4*>(&aggh1[(size_t)i * 64 + q * 8]);
        *reinterpret_cast<uint4*>(&At[m * LDA + q * 8]) = v;
    }
    for (int idx = tid; idx < 64; idx += 512) {          // agg1 -> [64,72)
        int m = idx;
        int i = node0 + m;
        uint4 v = make_uint4(0, 0, 0, 0);
        if (i < N) v = *reinterpret_cast<const uint4*>(&agg1[(size_t)i * 8]);
        *reinterpret_cast<uint4*>(&At[m * LDA + 64]) = v;
    }
    for (int idx = tid; idx < 64 * 16; idx += 512) {     // aggh2 -> [72,200)
        int m = idx >> 4, q = idx & 15;
        int i = node0 + m;
        uint4 v = make_uint4(0, 0, 0, 0);
        if (i < N) v = *reinterpret_cast<const uint4*>(&aggh2[(size_t)i * 128 + q * 8]);
        *reinterpret_cast<uint4*>(&At[m * LDA + 72 + q * 8]) = v;
    }
    for (int idx = tid; idx < 64 * 3; idx += 512) {      // zero pad [200,224)
        int m = idx / 3, q = idx - m * 3;
        *reinterpret_cast<uint4*>(&At[m * LDA + 200 + q * 8]) = make_uint4(0, 0, 0, 0);
    }
    if (tid < 64) batchv[tid] = (node0 + tid < N) ? batch[node0 + tid] : -1;
    __syncthreads();

    // ---- MFMA ----
    const int r15 = lane & 15, kg = lane >> 4;

    short8 a[2][KS];
    #pragma unroll
    for (int s = 0; s < 2; s++)
        #pragma unroll
        for (int kc = 0; kc < KS; kc++)
            a[s][kc] = *reinterpret_cast<const short8*>(
                &At[(wm * 32 + s * 16 + r15) * LDA + kg * 8 + kc * 32]);

    f32x4 acc[2][NT];
    #pragma unroll
    for (int s = 0; s < 2; s++)
        #pragma unroll
        for (int nt = 0; nt < NT; nt++) acc[s][nt] = (f32x4){0.f, 0.f, 0.f, 0.f};

    const ushort* wbase = &Wt[(size_t)(wn * FW + r15) * KPAD + kg * 8];
    #pragma unroll
    for (int nt = 0; nt < NT; nt++) {
        short8 b[KS];
        #pragma unroll
        for (int kc = 0; kc < KS; kc++)
            b[kc] = *reinterpret_cast<const short8*>(
                wbase + (size_t)nt * 16 * KPAD + kc * 32);
        #pragma unroll
        for (int kc = 0; kc < KS; kc++) {
            acc[0][nt] = __builtin_amdgcn_mfma_f32_16x16x32_bf16(a[0][kc], b[kc], acc[0][nt], 0, 0, 0);
            acc[1][nt] = __builtin_amdgcn_mfma_f32_16x16x32_bf16(a[1][kc], b[kc], acc[1][nt], 0, 0, 0);
        }
    }

    // ---- h3 tile -> LDS (reuse At; LDA >= 256) + segmented max pool ----
    __syncthreads();
    ushort* H3 = At;
    #pragma unroll
    for (int s = 0; s < 2; s++)
        #pragma unroll
        for (int nt = 0; nt < NT; nt++) {
            int colg = wn * FW + nt * 16 + r15;
            float bv = bias[colg];
            #pragma unroll
            for (int reg = 0; reg < 4; reg++) {
                int m = wm * 32 + s * 16 + kg * 4 + reg;
                float v = fmaxf(acc[s][nt][reg] + bv, 0.f);
                H3[m * 256 + colg] = f2bf(v);
            }
        }
    __syncthreads();
    int nvalid = min(64, N - node0);
    int c = tid & 255, half = tid >> 8;
    int m0 = half * 32;
    int m1 = min(m0 + 32, nvalid);
    int curg = -1;
    float cm = 0.f;
    for (int m = m0; m < m1; m++) {
        int g = batchv[m];
        if (g != curg) {
            if (curg >= 0)
                atomicMax(reinterpret_cast<int*>(&pooled[curg * 256 + c]),
                          __float_as_int(cm));
            curg = g;
            cm = 0.f;
        }
        cm = fmaxf(cm, __uint_as_float((uint)H3[m * 256 + c] << 16));
    }
    if (curg >= 0)
        atomicMax(reinterpret_cast<int*>(&pooled[curg * 256 + c]),
                  __float_as_int(cm));
}

// ---------------- head ----------------

__global__ __launch_bounds__(320) void head_k(const float* __restrict__ pooled,
                                              const float* __restrict__ Wl,
                                              const float* __restrict__ bl,
                                              float* __restrict__ out) {
    __shared__ float lg[GG][10];
    __shared__ float lse[GG];
    int t = threadIdx.x;
    int g = t / 10, c = t % 10;
    float acc = bl[c];
    for (int k = 0; k < 256; k++) acc = fmaf(pooled[g * 256 + k], Wl[k * 10 + c], acc);
    lg[g][c] = acc;
    __syncthreads();
    if (c == 0) {
        float mx = -1e30f;
        for (int j = 0; j < 10; j++) mx = fmaxf(mx, lg[g][j]);
        float s = 0.f;
        for (int j = 0; j < 10; j++) s += expf(lg[g][j] - mx);
        lse[g] = mx + logf(s);
    }
    __syncthreads();
    float o = acc - lse[g];
    out[g * 10 + c] = o;             // log_softmax
    out[320 + g * 10 + c] = expf(o); // softmax(log_softmax(x)) == exp(log_softmax(x))
}

// ---------------- launch ----------------

extern "C" void kernel_launch(void* const* d_in, const int* in_sizes, int n_in,
                              void* d_out, int out_size, void* d_ws, size_t ws_size,
                              hipStream_t stream) {
    const int N = NN, E = EE;
    const float* nrm = (const float*)d_in[0];
    const float* pos = (const float*)d_in[1];
    const float* x   = (const float*)d_in[2];
    const int* ei    = (const int*)d_in[3];
    const int* batch = (const int*)d_in[4];
    const float* W1 = (const float*)d_in[5];
    const float* b1 = (const float*)d_in[6];
    const float* W2 = (const float*)d_in[7];
    const float* b2 = (const float*)d_in[8];
    const float* W3 = (const float*)d_in[9];
    const float* b3 = (const float*)d_in[10];
    const float* Wl = (const float*)d_in[11];
    const float* bl = (const float*)d_in[12];

    const int* esrc = ei;
    const int* edst = ei + E;

    char* w = (char*)d_ws;
    auto carve = [&](size_t bytes) {
        void* p = (void*)w;
        w += (bytes + 255) & ~(size_t)255;
        return p;
    };
    int* hist     = (int*)carve((size_t)MH * 4);
    int* ofs      = (int*)carve((size_t)MH * 4);
    int* bsum     = (int*)carve((size_t)NB2 * 4);
    uint* packed  = (uint*)carve((size_t)E * 4);
    int* rowptr   = (int*)carve((size_t)(N + 1) * 4);
    ushort* col   = (ushort*)carve((size_t)E * 2);
    ushort* inpb  = (ushort*)carve((size_t)N * 8 * 2);
    ushort* agg1  = (ushort*)carve((size_t)N * 8 * 2);
    ushort* h1    = (ushort*)carve((size_t)N * 64 * 2);
    ushort* aggh1 = (ushort*)carve((size_t)N * 64 * 2);
    ushort* h2    = (ushort*)carve((size_t)N * 128 * 2);
    ushort* aggh2 = (ushort*)carve((size_t)N * 128 * 2);
    ushort* Wt1   = (ushort*)carve((size_t)64 * 32 * 2);
    ushort* Wt2   = (ushort*)carve((size_t)128 * 96 * 2);
    ushort* Wt3   = (ushort*)carve((size_t)256 * 224 * 2);
    float* pooled = (float*)carve((size_t)GG * 256 * 4);

    // setup: bhist | inp | Wt | pooled-init (one dispatch)
    setup_k<<<NBLK1 + B_PREP + B_WTP + 1, 256, 0, stream>>>(
        edst, hist, nrm, pos, x, inpb, W1, Wt1, W2, Wt2, W3, Wt3, pooled);

    // CSR via two-level bucket sort
    scan1_k<<<NB2, SCB, 0, stream>>>(hist, bsum, MH);
    scan2g_k<<<1, 64, 0, stream>>>(bsum, NB2);
    scan3g_k<<<NB2, SCB, 0, stream>>>(hist, bsum, ofs, MH);
    bsort1_k<<<NBLK1, 256, 0, stream>>>(esrc, edst, ofs, packed);
    bsort2_k<<<NBUK, 256, 0, stream>>>(packed, ofs, col, rowptr);

    // layer 1: A = [agg(inp)(8)]            -> h1, agg1
    layer_k<8, 32, 40, 64, 0, 0, 8><<<NBUK, 512, 0, stream>>>(
        nullptr, nullptr, inpb, rowptr, col, Wt1, b1, agg1, h1, N);

    // layer 2: A = [agg1(8) | agg(h1)(64)]  -> h2, aggh1   (Wt2 K-permuted)
    layer_k<72, 96, 104, 128, 8, 0, 64><<<NBUK, 512, 0, stream>>>(
        agg1, nullptr, h1, rowptr, col, Wt2, b2, aggh1, h2, N);

    // layer 3a: standalone high-TLP gather  -> aggh2
    gather3_k<<<(N + 31) / 32, 256, 0, stream>>>(rowptr, col, h2, aggh2, N);

    // layer 3b: MFMA + fused pool
    layer3b_k<<<NBUK, 512, 0, stream>>>(aggh1, agg1, aggh2, Wt3, b3, batch, pooled, N);

    head_k<<<1, 320, 0, stream>>>(pooled, Wl, bl, (float*)d_out);
}

// Round 15
// 133.416 us; speedup vs baseline: 1.0689x; 1.0689x over previous
//
#include <hip/hip_runtime.h>
#include <hip/hip_bf16.h>

#define NN 50000
#define EE 800000
#define GG 32
#define SCB 512

// bucket sort geometry (bucket = 64 dst nodes = one layer-block)
#define BSH 6
#define NBUK 782                      // ceil(50000/64)
#define NBLK1 256                     // edge blocks in pass 1
#define EPB (EE / NBLK1)              // 3125 edges per block
#define MH (NBUK * NBLK1)             // 200192 counters
#define NB2 ((MH + SCB - 1) / SCB)    // 391 scan blocks
#define CAP2 2048                     // max edges per bucket (mean 1023)

#define B_PREP ((NN + 255) / 256)                 // 196
#define TOTW (64 * 32 + 128 * 96 + 256 * 224)     // 71680
#define B_WTP ((TOTW + 255) / 256)                // 280

using short8 = __attribute__((ext_vector_type(8))) short;
using f32x4  = __attribute__((ext_vector_type(4))) float;

__device__ __forceinline__ ushort f2bf(float f) {
    __hip_bfloat16 hb = __float2bfloat16(f);
    return *reinterpret_cast<ushort*>(&hb);
}

__device__ __forceinline__ void acc8(uint4 v, float* a) {
    a[0] += __uint_as_float(v.x << 16); a[1] += __uint_as_float(v.x & 0xffff0000u);
    a[2] += __uint_as_float(v.y << 16); a[3] += __uint_as_float(v.y & 0xffff0000u);
    a[4] += __uint_as_float(v.z << 16); a[5] += __uint_as_float(v.z & 0xffff0000u);
    a[6] += __uint_as_float(v.w << 16); a[7] += __uint_as_float(v.w & 0xffff0000u);
}

// Wt[n][k'] = W[k][n]; mode 1 = fold W3 rows 200:208 into 64:72;
// mode 2 = layer-2 K-permutation so A-layout is [agg1(8)|aggh1(64)].
__device__ __forceinline__ void wtp_one(const float* W, ushort* Wt, int K, int F,
                                        int KPAD, int mode, int idx) {
    int n = idx / KPAD, k = idx - n * KPAD;
    float v = 0.f;
    if (k < K) {
        int ko = k;
        if (mode == 2) ko = (k < 8) ? (k + 64) : (k - 8);
        v = W[(size_t)ko * F + n];
        if (mode == 1 && ko >= 64 && ko < 72) v += W[(size_t)(ko + 136) * F + n];
    }
    Wt[idx] = f2bf(v);
}

// ---------------- fused setup: bhist | inp-build | Wt build | pooled init ----------------

__global__ __launch_bounds__(256) void setup_k(
        const int* __restrict__ edst, int* __restrict__ hist,
        const float* __restrict__ nrm, const float* __restrict__ pos,
        const float* __restrict__ x, ushort* __restrict__ inpb,
        const float* __restrict__ W1, ushort* __restrict__ Wt1,
        const float* __restrict__ W2, ushort* __restrict__ Wt2,
        const float* __restrict__ W3, ushort* __restrict__ Wt3,
        float* __restrict__ pooled) {
    int blk = blockIdx.x, tid = threadIdx.x;
    if (blk < NBLK1) {
        __shared__ uint cnt[NBUK];
        for (int i = tid; i < NBUK; i += 256) cnt[i] = 0;
        __syncthreads();
        int base = blk * EPB;
        for (int i = tid; i < EPB; i += 256)
            atomicAdd(&cnt[(uint)edst[base + i] >> BSH], 1u);
        __syncthreads();
        for (int b = tid; b < NBUK; b += 256)
            hist[(size_t)b * NBLK1 + blk] = (int)cnt[b];
    } else if (blk < NBLK1 + B_PREP) {
        int i = (blk - NBLK1) * 256 + tid;
        if (i < NN) {
            float v[8];
            v[0] = nrm[i * 3]; v[1] = nrm[i * 3 + 1]; v[2] = nrm[i * 3 + 2];
            v[3] = pos[i * 3]; v[4] = pos[i * 3 + 1]; v[5] = pos[i * 3 + 2];
            v[6] = x[i * 2];   v[7] = x[i * 2 + 1];
            uint4 d;
            d.x = (uint)f2bf(v[0]) | ((uint)f2bf(v[1]) << 16);
            d.y = (uint)f2bf(v[2]) | ((uint)f2bf(v[3]) << 16);
            d.z = (uint)f2bf(v[4]) | ((uint)f2bf(v[5]) << 16);
            d.w = (uint)f2bf(v[6]) | ((uint)f2bf(v[7]) << 16);
            *reinterpret_cast<uint4*>(&inpb[(size_t)i * 8]) = d;
        }
    } else if (blk < NBLK1 + B_PREP + B_WTP) {
        int idx = (blk - NBLK1 - B_PREP) * 256 + tid;
        if (idx < 64 * 32) { wtp_one(W1, Wt1, 8, 64, 32, 0, idx); return; }
        idx -= 64 * 32;
        if (idx < 128 * 96) { wtp_one(W2, Wt2, 72, 128, 96, 2, idx); return; }
        idx -= 128 * 96;
        if (idx < 256 * 224) wtp_one(W3, Wt3, 200, 256, 224, 1, idx);
    } else {
        for (int q = tid; q < GG * 256; q += 256) pooled[q] = 0.f;
    }
}

// ---------------- generic 3-phase exclusive scan ----------------

__global__ __launch_bounds__(SCB) void scan1_k(const int* __restrict__ in,
                                               int* __restrict__ bsum, int M) {
    __shared__ int ws[SCB / 64];
    int tid = threadIdx.x, lane = tid & 63, w = tid >> 6;
    int i = blockIdx.x * SCB + tid;
    int s = (i < M) ? in[i] : 0;
    #pragma unroll
    for (int off = 32; off >= 1; off >>= 1) s += __shfl_down(s, off, 64);
    if (lane == 0) ws[w] = s;
    __syncthreads();
    if (tid == 0) {
        int t = 0;
        #pragma unroll
        for (int j = 0; j < SCB / 64; j++) t += ws[j];
        bsum[blockIdx.x] = t;
    }
}

__global__ __launch_bounds__(64) void scan2g_k(int* __restrict__ bsum, int nb) {
    int lane = threadIdx.x;
    int carry = 0;
    for (int base = 0; base < nb; base += 64) {
        int v = (base + lane < nb) ? bsum[base + lane] : 0;
        int s = v;
        #pragma unroll
        for (int off = 1; off < 64; off <<= 1) {
            int t = __shfl_up(s, off, 64);
            if (lane >= off) s += t;
        }
        if (base + lane < nb) bsum[base + lane] = carry + s - v;
        carry += __shfl(s, 63, 64);
    }
}

__global__ __launch_bounds__(SCB) void scan3g_k(const int* __restrict__ in,
                                                const int* __restrict__ bsum,
                                                int* __restrict__ out, int M) {
    __shared__ int ws[SCB / 64];
    int tid = threadIdx.x, lane = tid & 63, w = tid >> 6;
    int i = blockIdx.x * SCB + tid;
    int v = (i < M) ? in[i] : 0;
    int s = v;
    #pragma unroll
    for (int off = 1; off < 64; off <<= 1) {
        int t = __shfl_up(s, off, 64);
        if (lane >= off) s += t;
    }
    if (lane == 63) ws[w] = s;
    __syncthreads();
    if (w == 0 && lane < SCB / 64) {
        int t = ws[lane];
        #pragma unroll
        for (int off = 1; off < SCB / 64; off <<= 1) {
            int u = __shfl_up(t, off, 64);
            if (lane >= off) t += u;
        }
        ws[lane] = t;
    }
    __syncthreads();
    if (i < M) out[i] = (w ? ws[w - 1] : 0) + s - v + bsum[blockIdx.x];
}

// ---------------- bucket sort pass 1 ----------------

__global__ __launch_bounds__(256) void bsort1_k(const int* __restrict__ esrc,
                                                const int* __restrict__ edst,
                                                const int* __restrict__ ofs,
                                                uint* __restrict__ packed) {
    __shared__ uint cnt[1024];
    __shared__ uint lofs0[1024];
    __shared__ uint goff[NBUK];
    __shared__ uint stage[EPB];
    __shared__ uint wsum[4];
    int tid = threadIdx.x, blk = blockIdx.x;
    int lane = tid & 63, wv = tid >> 6;

    for (int i = tid; i < 1024; i += 256) cnt[i] = 0;
    __syncthreads();
    int base = blk * EPB;
    for (int i = tid; i < EPB; i += 256)
        atomicAdd(&cnt[(uint)edst[base + i] >> BSH], 1u);
    __syncthreads();

    uint c0 = cnt[tid * 4 + 0], c1 = cnt[tid * 4 + 1];
    uint c2 = cnt[tid * 4 + 2], c3 = cnt[tid * 4 + 3];
    uint ts = c0 + c1 + c2 + c3;
    uint sc = ts;
    #pragma unroll
    for (int off = 1; off < 64; off <<= 1) {
        uint t = __shfl_up(sc, off, 64);
        if (lane >= off) sc += t;
    }
    if (lane == 63) wsum[wv] = sc;
    __syncthreads();
    uint wbase = 0;
    for (int j = 0; j < wv; j++) wbase += wsum[j];
    uint run = wbase + sc - ts;
    lofs0[tid * 4 + 0] = run;
    lofs0[tid * 4 + 1] = run + c0;
    lofs0[tid * 4 + 2] = run + c0 + c1;
    lofs0[tid * 4 + 3] = run + c0 + c1 + c2;
    cnt[tid * 4 + 0] = run;
    cnt[tid * 4 + 1] = run + c0;
    cnt[tid * 4 + 2] = run + c0 + c1;
    cnt[tid * 4 + 3] = run + c0 + c1 + c2;
    for (int b = tid; b < NBUK; b += 256)
        goff[b] = (uint)ofs[(size_t)b * NBLK1 + blk];
    __syncthreads();

    for (int i = tid; i < EPB; i += 256) {
        int d = edst[base + i];
        uint b = (uint)d >> BSH;
        uint pos = atomicAdd(&cnt[b], 1u);
        stage[pos] = (b << 22) | ((uint)(d & 63) << 16) | (uint)esrc[base + i];
    }
    __syncthreads();

    for (int i = tid; i < EPB; i += 256) {
        uint p = stage[i];
        uint b = p >> 22;
        packed[goff[b] + ((uint)i - lofs0[b])] = p & 0x3FFFFFu;
    }
}

// ---------------- bucket sort pass 2 ----------------

__global__ __launch_bounds__(256) void bsort2_k(const uint* __restrict__ packed,
                                                const int* __restrict__ ofs,
                                                ushort* __restrict__ col,
                                                int* __restrict__ rowptr) {
    __shared__ uint buf[CAP2];
    __shared__ ushort srt[CAP2];
    __shared__ uint fcnt[64], fofs[64];
    int b = blockIdx.x, tid = threadIdx.x;
    uint g0 = (uint)ofs[(size_t)b * NBLK1];
    uint g1 = (b + 1 < NBUK) ? (uint)ofs[(size_t)(b + 1) * NBLK1] : (uint)EE;
    uint n = g1 - g0;
    if (tid < 64) fcnt[tid] = 0;
    __syncthreads();
    for (uint i = tid; i < n; i += 256) {
        uint p = packed[g0 + i];
        buf[i] = p;
        atomicAdd(&fcnt[(p >> 16) & 63], 1u);
    }
    __syncthreads();
    if (tid < 64) {
        uint v = fcnt[tid], s = v;
        #pragma unroll
        for (int off = 1; off < 64; off <<= 1) {
            uint t = __shfl_up(s, off, 64);
            if (tid >= off) s += t;
        }
        uint e0 = s - v;
        fofs[tid] = e0;
        int node = (b << BSH) + tid;
        if (node < NN) rowptr[node] = (int)(g0 + e0);
    }
    if (b == NBUK - 1 && tid == 0) rowptr[NN] = EE;
    __syncthreads();
    for (uint i = tid; i < n; i += 256) {
        uint p = buf[i];
        uint pos = atomicAdd(&fofs[(p >> 16) & 63], 1u);
        srt[pos] = (ushort)(p & 0xFFFFu);
    }
    __syncthreads();
    for (uint i = tid; i < n; i += 256) col[g0 + i] = srt[i];
}

// ---------------- fused layer: gather-aggregate + MFMA transform (+ pool) ----------------
// R8 structure with R13's 4-edge load batching in phase A. Block = 64 nodes
// (one bucket), 512 threads = 8 waves. Phase B: 2(M)x4(N) wave grid, B-loads
// batched KS-deep (R6 lesson). Fragment layouts (m89/m91-verified): A/B lane
// l -> row l&15, k=(l>>4)*8+e; C/D col=lane&15, row=(lane>>4)*4+reg.
// POOL: h3 tile reuses At (LDA>=256); segmented max over sorted batch.
// NOTE (R14 post-mortem): splitting the L3 gather out (high-TLP standalone)
// REGRESSED (142.6 vs 134.4); slice/XCD partitioning and node-splitting also
// regressed. The ~52us L3 kernel is a structural floor: 800k random 256B-row
// reads, >=78MB compulsory beyond-L2 traffic at ~1.5TB/s effective.

template <int K, int KPAD, int LDA, int F, int WPA, int WPB, int WG, bool POOL>
__global__ __launch_bounds__(512) void layer_k(
        const ushort* __restrict__ preA, const ushort* __restrict__ preB,
        const ushort* __restrict__ gsrc,
        const int* __restrict__ rowptr, const ushort* __restrict__ col,
        const ushort* __restrict__ Wt, const float* __restrict__ bias,
        ushort* __restrict__ aggout, ushort* __restrict__ out,
        const int* __restrict__ batch, float* __restrict__ pooled, int N) {
    constexpr int WPRE = WPA + WPB;
    constexpr int NU4 = WG / 8;
    constexpr int TPN = (NU4 < 8) ? NU4 : 8;
    constexpr int U4PT = NU4 / TPN;
    constexpr int KS = KPAD / 32;
    constexpr int FW = F / 4;
    constexpr int NT = FW / 16;

    __shared__ ushort At[64 * LDA];
    __shared__ int batchv[64];

    const int node0 = blockIdx.x * 64;
    const int tid = threadIdx.x;
    const int lane = tid & 63;
    const int wv = tid >> 6;
    const int wm = wv & 1;
    const int wn = wv >> 1;

    // ---- phase A: gather-aggregate into At[., WPRE..WPRE+WG) ----
    {
        int m = tid / TPN;
        int j = tid - m * TPN;
        if (m < 64) {
            int i = node0 + m;
            float ga0[U4PT * 8], ga1[U4PT * 8];
            #pragma unroll
            for (int q = 0; q < U4PT * 8; q++) { ga0[q] = 0.f; ga1[q] = 0.f; }
            if (i < N) {
                int e0 = rowptr[i], e1 = rowptr[i + 1];
                int e = e0;
                // 4-edge batch: issue all 4*U4PT loads, then accumulate
                for (; e + 3 < e1; e += 4) {
                    int s0 = col[e], s1 = col[e + 1], s2 = col[e + 2], s3 = col[e + 3];
                    uint4 v0[U4PT], v1[U4PT], v2[U4PT], v3[U4PT];
                    #pragma unroll
                    for (int u = 0; u < U4PT; u++) {
                        v0[u] = *reinterpret_cast<const uint4*>(
                            &gsrc[(size_t)s0 * WG + (j * U4PT + u) * 8]);
                        v1[u] = *reinterpret_cast<const uint4*>(
                            &gsrc[(size_t)s1 * WG + (j * U4PT + u) * 8]);
                        v2[u] = *reinterpret_cast<const uint4*>(
                            &gsrc[(size_t)s2 * WG + (j * U4PT + u) * 8]);
                        v3[u] = *reinterpret_cast<const uint4*>(
                            &gsrc[(size_t)s3 * WG + (j * U4PT + u) * 8]);
                    }
                    #pragma unroll
                    for (int u = 0; u < U4PT; u++) {
                        acc8(v0[u], ga0 + u * 8);
                        acc8(v1[u], ga1 + u * 8);
                        acc8(v2[u], ga0 + u * 8);
                        acc8(v3[u], ga1 + u * 8);
                    }
                }
                for (; e + 1 < e1; e += 2) {
                    int s0 = col[e], s1 = col[e + 1];
                    uint4 v0[U4PT], v1[U4PT];
                    #pragma unroll
                    for (int u = 0; u < U4PT; u++) {
                        v0[u] = *reinterpret_cast<const uint4*>(
                            &gsrc[(size_t)s0 * WG + (j * U4PT + u) * 8]);
                        v1[u] = *reinterpret_cast<const uint4*>(
                            &gsrc[(size_t)s1 * WG + (j * U4PT + u) * 8]);
                    }
                    #pragma unroll
                    for (int u = 0; u < U4PT; u++) {
                        acc8(v0[u], ga0 + u * 8);
                        acc8(v1[u], ga1 + u * 8);
                    }
                }
                if (e < e1) {
                    int s0 = col[e];
                    #pragma unroll
                    for (int u = 0; u < U4PT; u++) {
                        uint4 v0 = *reinterpret_cast<const uint4*>(
                            &gsrc[(size_t)s0 * WG + (j * U4PT + u) * 8]);
                        acc8(v0, ga0 + u * 8);
                    }
                }
            }
            #pragma unroll
            for (int u = 0; u < U4PT; u++) {
                uint4 o;
                o.x = (uint)f2bf(ga0[u*8+0] + ga1[u*8+0]) | ((uint)f2bf(ga0[u*8+1] + ga1[u*8+1]) << 16);
                o.y = (uint)f2bf(ga0[u*8+2] + ga1[u*8+2]) | ((uint)f2bf(ga0[u*8+3] + ga1[u*8+3]) << 16);
                o.z = (uint)f2bf(ga0[u*8+4] + ga1[u*8+4]) | ((uint)f2bf(ga0[u*8+5] + ga1[u*8+5]) << 16);
                o.w = (uint)f2bf(ga0[u*8+6] + ga1[u*8+6]) | ((uint)f2bf(ga0[u*8+7] + ga1[u*8+7]) << 16);
                *reinterpret_cast<uint4*>(&At[m * LDA + WPRE + (j * U4PT + u) * 8]) = o;
                if (aggout != nullptr && i < N)
                    *reinterpret_cast<uint4*>(&aggout[(size_t)i * WG + (j * U4PT + u) * 8]) = o;
            }
        }
        if constexpr (POOL) {
            if (tid < 64) batchv[tid] = (node0 + tid < N) ? batch[node0 + tid] : -1;
        }
    }

    // ---- pre-staged cols [0, WPRE) from global ----
    if constexpr (WPRE > 0) {
        constexpr int NP = WPRE / 8;
        for (int idx = tid; idx < 64 * NP; idx += 512) {
            int m = idx / NP, q = idx - m * NP;
            int i = node0 + m;
            uint4 v = make_uint4(0, 0, 0, 0);
            if (i < N) {
                int c = q * 8;
                if (c < WPA) v = *reinterpret_cast<const uint4*>(&preA[(size_t)i * WPA + c]);
                else v = *reinterpret_cast<const uint4*>(&preB[(size_t)i * WPB + (c - WPA)]);
            }
            *reinterpret_cast<uint4*>(&At[m * LDA + q * 8]) = v;
        }
    }
    // ---- zero pad [K, LDA) ----
    {
        constexpr int PAD = LDA - K;
        for (int idx = tid; idx < 64 * PAD; idx += 512) {
            int m = idx / PAD, k = K + (idx - m * PAD);
            At[m * LDA + k] = 0;
        }
    }
    __syncthreads();

    // ---- phase B: MFMA ----
    const int r15 = lane & 15, kg = lane >> 4;

    short8 a[2][KS];
    #pragma unroll
    for (int s = 0; s < 2; s++)
        #pragma unroll
        for (int kc = 0; kc < KS; kc++)
            a[s][kc] = *reinterpret_cast<const short8*>(
                &At[(wm * 32 + s * 16 + r15) * LDA + kg * 8 + kc * 32]);

    f32x4 acc[2][NT];
    #pragma unroll
    for (int s = 0; s < 2; s++)
        #pragma unroll
        for (int nt = 0; nt < NT; nt++) acc[s][nt] = (f32x4){0.f, 0.f, 0.f, 0.f};

    const ushort* wbase = &Wt[(size_t)(wn * FW + r15) * KPAD + kg * 8];
    #pragma unroll
    for (int nt = 0; nt < NT; nt++) {
        short8 b[KS];
        #pragma unroll
        for (int kc = 0; kc < KS; kc++)
            b[kc] = *reinterpret_cast<const short8*>(
                wbase + (size_t)nt * 16 * KPAD + kc * 32);
        #pragma unroll
        for (int kc = 0; kc < KS; kc++) {
            acc[0][nt] = __builtin_amdgcn_mfma_f32_16x16x32_bf16(a[0][kc], b[kc], acc[0][nt], 0, 0, 0);
            acc[1][nt] = __builtin_amdgcn_mfma_f32_16x16x32_bf16(a[1][kc], b[kc], acc[1][nt], 0, 0, 0);
        }
    }

    if constexpr (!POOL) {
        #pragma unroll
        for (int s = 0; s < 2; s++)
            #pragma unroll
            for (int nt = 0; nt < NT; nt++) {
                int colg = wn * FW + nt * 16 + r15;
                float bv = bias[colg];
                #pragma unroll
                for (int reg = 0; reg < 4; reg++) {
                    int row = node0 + wm * 32 + s * 16 + kg * 4 + reg;
                    if (row < N) {
                        float v = fmaxf(acc[s][nt][reg] + bv, 0.f);
                        out[(size_t)row * F + colg] = f2bf(v);
                    }
                }
            }
    } else {
        // h3 tile -> LDS (reuse At; LDA >= 256), then segmented max pool
        __syncthreads();
        ushort* H3 = At;
        #pragma unroll
        for (int s = 0; s < 2; s++)
            #pragma unroll
            for (int nt = 0; nt < NT; nt++) {
                int colg = wn * FW + nt * 16 + r15;
                float bv = bias[colg];
                #pragma unroll
                for (int reg = 0; reg < 4; reg++) {
                    int m = wm * 32 + s * 16 + kg * 4 + reg;
                    float v = fmaxf(acc[s][nt][reg] + bv, 0.f);
                    H3[m * 256 + colg] = f2bf(v);
                }
            }
        __syncthreads();
        int nvalid = min(64, N - node0);
        int c = tid & 255, half = tid >> 8;
        int m0 = half * 32;
        int m1 = min(m0 + 32, nvalid);
        int curg = -1;
        float cm = 0.f;
        for (int m = m0; m < m1; m++) {
            int g = batchv[m];
            if (g != curg) {
                if (curg >= 0)
                    atomicMax(reinterpret_cast<int*>(&pooled[curg * 256 + c]),
                              __float_as_int(cm));
                curg = g;
                cm = 0.f;
            }
            cm = fmaxf(cm, __uint_as_float((uint)H3[m * 256 + c] << 16));
        }
        if (curg >= 0)
            atomicMax(reinterpret_cast<int*>(&pooled[curg * 256 + c]),
                      __float_as_int(cm));
    }
}

// ---------------- head ----------------

__global__ __launch_bounds__(320) void head_k(const float* __restrict__ pooled,
                                              const float* __restrict__ Wl,
                                              const float* __restrict__ bl,
                                              float* __restrict__ out) {
    __shared__ float lg[GG][10];
    __shared__ float lse[GG];
    int t = threadIdx.x;
    int g = t / 10, c = t % 10;
    float acc = bl[c];
    for (int k = 0; k < 256; k++) acc = fmaf(pooled[g * 256 + k], Wl[k * 10 + c], acc);
    lg[g][c] = acc;
    __syncthreads();
    if (c == 0) {
        float mx = -1e30f;
        for (int j = 0; j < 10; j++) mx = fmaxf(mx, lg[g][j]);
        float s = 0.f;
        for (int j = 0; j < 10; j++) s += expf(lg[g][j] - mx);
        lse[g] = mx + logf(s);
    }
    __syncthreads();
    float o = acc - lse[g];
    out[g * 10 + c] = o;             // log_softmax
    out[320 + g * 10 + c] = expf(o); // softmax(log_softmax(x)) == exp(log_softmax(x))
}

// ---------------- launch ----------------

extern "C" void kernel_launch(void* const* d_in, const int* in_sizes, int n_in,
                              void* d_out, int out_size, void* d_ws, size_t ws_size,
                              hipStream_t stream) {
    const int N = NN, E = EE;
    const float* nrm = (const float*)d_in[0];
    const float* pos = (const float*)d_in[1];
    const float* x   = (const float*)d_in[2];
    const int* ei    = (const int*)d_in[3];
    const int* batch = (const int*)d_in[4];
    const float* W1 = (const float*)d_in[5];
    const float* b1 = (const float*)d_in[6];
    const float* W2 = (const float*)d_in[7];
    const float* b2 = (const float*)d_in[8];
    const float* W3 = (const float*)d_in[9];
    const float* b3 = (const float*)d_in[10];
    const float* Wl = (const float*)d_in[11];
    const float* bl = (const float*)d_in[12];

    const int* esrc = ei;
    const int* edst = ei + E;

    char* w = (char*)d_ws;
    auto carve = [&](size_t bytes) {
        void* p = (void*)w;
        w += (bytes + 255) & ~(size_t)255;
        return p;
    };
    int* hist     = (int*)carve((size_t)MH * 4);
    int* ofs      = (int*)carve((size_t)MH * 4);
    int* bsum     = (int*)carve((size_t)NB2 * 4);
    uint* packed  = (uint*)carve((size_t)E * 4);
    int* rowptr   = (int*)carve((size_t)(N + 1) * 4);
    ushort* col   = (ushort*)carve((size_t)E * 2);
    ushort* inpb  = (ushort*)carve((size_t)N * 8 * 2);
    ushort* agg1  = (ushort*)carve((size_t)N * 8 * 2);
    ushort* h1    = (ushort*)carve((size_t)N * 64 * 2);
    ushort* aggh1 = (ushort*)carve((size_t)N * 64 * 2);
    ushort* h2    = (ushort*)carve((size_t)N * 128 * 2);
    ushort* Wt1   = (ushort*)carve((size_t)64 * 32 * 2);
    ushort* Wt2   = (ushort*)carve((size_t)128 * 96 * 2);
    ushort* Wt3   = (ushort*)carve((size_t)256 * 224 * 2);
    float* pooled = (float*)carve((size_t)GG * 256 * 4);

    // setup: bhist | inp | Wt | pooled-init (one dispatch)
    setup_k<<<NBLK1 + B_PREP + B_WTP + 1, 256, 0, stream>>>(
        edst, hist, nrm, pos, x, inpb, W1, Wt1, W2, Wt2, W3, Wt3, pooled);

    // CSR via two-level bucket sort
    scan1_k<<<NB2, SCB, 0, stream>>>(hist, bsum, MH);
    scan2g_k<<<1, 64, 0, stream>>>(bsum, NB2);
    scan3g_k<<<NB2, SCB, 0, stream>>>(hist, bsum, ofs, MH);
    bsort1_k<<<NBLK1, 256, 0, stream>>>(esrc, edst, ofs, packed);
    bsort2_k<<<NBUK, 256, 0, stream>>>(packed, ofs, col, rowptr);

    // layer 1: A = [agg(inp)(8)]            -> h1, agg1
    layer_k<8, 32, 40, 64, 0, 0, 8, false><<<NBUK, 512, 0, stream>>>(
        nullptr, nullptr, inpb, rowptr, col, Wt1, b1, agg1, h1, nullptr, nullptr, N);

    // layer 2: A = [agg1(8) | agg(h1)(64)]  -> h2, aggh1   (Wt2 K-permuted)
    layer_k<72, 96, 104, 128, 8, 0, 64, false><<<NBUK, 512, 0, stream>>>(
        agg1, nullptr, h1, rowptr, col, Wt2, b2, aggh1, h2, nullptr, nullptr, N);

    // layer 3: A = [aggh1(64) | agg1(8) | agg(h2)(128)] -> pooled (fused max pool)
    layer_k<200, 224, 264, 256, 64, 8, 128, true><<<NBUK, 512, 0, stream>>>(
        aggh1, agg1, h2, rowptr, col, Wt3, b3, nullptr, nullptr, batch, pooled, N);

    head_k<<<1, 320, 0, stream>>>(pooled, Wl, bl, (float*)d_out);
}